// Round 10
// baseline (374.047 us; speedup 1.0000x reference)
//
#include <hip/hip_runtime.h>
#include <hip/hip_bf16.h>

// Transformer block fwd: x:[2,2048,1024] fp32. bf16 MFMA GEMMs + flash attn.
// E=1024 H=16 D=64 HID=4096, causal, exact GELU, LN eps=1e-6.

#define E_    1024
#define TE_   3072
#define S_    2048
#define B_    2
#define H_    16
#define MROWS 4096   // B*S

typedef __attribute__((ext_vector_type(8))) short bf16x8;
typedef __attribute__((ext_vector_type(4))) short short4v;
typedef __attribute__((ext_vector_type(4))) float f32x4;

__device__ __forceinline__ short f2bf(float f) {
  union { float f; unsigned u; } v; v.f = f;
  unsigned r = v.u + 0x7fffu + ((v.u >> 16) & 1u);  // RNE
  return (short)(r >> 16);
}
__device__ __forceinline__ float bf2f(short s) {
  union { unsigned u; float f; } v; v.u = ((unsigned)(unsigned short)s) << 16;
  return v.f;
}
__device__ __forceinline__ void gload_lds16(const void* g, void* l) {
  __builtin_amdgcn_global_load_lds(
      (const __attribute__((address_space(1))) unsigned int*)g,
      (__attribute__((address_space(3))) unsigned int*)l, 16, 0, 0);
}
__device__ __forceinline__ float exp2_fast(float x) {  // exact v_exp_f32 (2^x)
  float r; asm("v_exp_f32 %0, %1" : "=v"(r) : "v"(x)); return r;
}
__device__ __forceinline__ float gelu_f(float v) {
  return 0.5f * v * (1.0f + erff(v * 0.70710678118654752f));
}

// ---------------- fp32 -> bf16 weight convert (4 tensors fused) -----------
__global__ __launch_bounds__(256) void k_cvt4(const float* __restrict__ i0, short* __restrict__ o0, int n0,
                                              const float* __restrict__ i1, short* __restrict__ o1, int n1,
                                              const float* __restrict__ i2, short* __restrict__ o2, int n2,
                                              const float* __restrict__ i3, short* __restrict__ o3, int n3) {
  const float* in; short* out; int n;
  switch (blockIdx.y) {
    case 0: in = i0; out = o0; n = n0; break;
    case 1: in = i1; out = o1; n = n1; break;
    case 2: in = i2; out = o2; n = n2; break;
    default: in = i3; out = o3; n = n3; break;
  }
  int i = blockIdx.x * 256 + threadIdx.x;
  if (i >= n) return;
  float4 v = ((const float4*)in)[i];
  short4v o = { f2bf(v.x), f2bf(v.y), f2bf(v.z), f2bf(v.w) };
  ((short4v*)out)[i] = o;
}

// ---------------- LayerNorm fp32 -> bf16 ----------------
__global__ __launch_bounds__(256) void k_ln(const float* __restrict__ x,
                                            const float* __restrict__ w,
                                            const float* __restrict__ b,
                                            short* __restrict__ out) {
  int row = blockIdx.x;
  int tid = threadIdx.x;
  float4 v = ((const float4*)(x + (size_t)row * E_))[tid];
  float s  = v.x + v.y + v.z + v.w;
  float s2 = v.x*v.x + v.y*v.y + v.z*v.z + v.w*v.w;
  #pragma unroll
  for (int d = 1; d < 64; d <<= 1) { s += __shfl_xor(s, d); s2 += __shfl_xor(s2, d); }
  __shared__ float rs[4], rq[4];
  int wv = tid >> 6;
  if ((tid & 63) == 0) { rs[wv] = s; rq[wv] = s2; }
  __syncthreads();
  s  = rs[0] + rs[1] + rs[2] + rs[3];
  s2 = rq[0] + rq[1] + rq[2] + rq[3];
  float mu  = s * (1.0f / E_);
  float var = fmaxf(s2 * (1.0f / E_) - mu * mu, 0.0f);
  float inv = rsqrtf(var + 1e-6f);
  float4 wv4 = ((const float4*)w)[tid];
  float4 bv4 = ((const float4*)b)[tid];
  short4v o = { f2bf((v.x - mu) * inv * wv4.x + bv4.x),
                f2bf((v.y - mu) * inv * wv4.y + bv4.y),
                f2bf((v.z - mu) * inv * wv4.z + bv4.z),
                f2bf((v.w - mu) * inv * wv4.w + bv4.w) };
  ((short4v*)(out + (size_t)row * E_))[tid] = o;
}

// ---------------- bf16 GEMM: out[m,n] = sum_k A[m,k]*W[n,k] (+epilogue) ----
// 512 threads (8 waves 2Mx4N), BM=BN=128, BK=64. Depth-2 counted-vmcnt
// pipeline (T3/T4). LDS chunk-XOR swizzle applied both-sides.
// EPI: 0 = +bias -> bf16 ; 1 = +bias+res -> fp32 ; 2 = +bias, gelu -> bf16
template <int EPI>
__global__ __launch_bounds__(512, 2) void k_gemm(const short* __restrict__ A,
                                                 const short* __restrict__ W,
                                                 const float* __restrict__ bias,
                                                 const float* __restrict__ res,
                                                 void* __restrict__ outv,
                                                 int M, int N, int K) {
  __shared__ short As[2][8192];   // [128 rows][64 k] bf16, swizzled
  __shared__ short Ws[2][8192];
  int tid  = threadIdx.x;
  int lane = tid & 63, wave = tid >> 6;
  int wm = wave >> 2, wn = wave & 3;       // 2 x 4 wave grid
  // XCD-aware bijective block swizzle (all grids have nwg % 8 == 0)
  int nwg = (int)(gridDim.x * gridDim.y);
  int id  = (int)(blockIdx.y * gridDim.x + blockIdx.x);
  int qc  = nwg >> 3;
  int sid = (id & 7) * qc + (id >> 3);
  int bx = sid % (int)gridDim.x, by = sid / (int)gridDim.x;
  int m0 = by * 128, n0 = bx * 128;
  int fr = lane & 15, fq = lane >> 4;      // frag row / k-group
  int fp = fr & 7;                          // row parity for swizzle

  f32x4 acc[4][2];
  #pragma unroll
  for (int i = 0; i < 4; ++i)
    #pragma unroll
    for (int j = 0; j < 2; ++j) acc[i][j] = (f32x4){0.f, 0.f, 0.f, 0.f};

  int srow = tid >> 3;                      // staging row 0..63 (+64 2nd call)
  int swz  = ((tid & 7) ^ (srow & 7)) << 3; // pre-swizzled source chunk
  const short* Asrc = A + (size_t)(m0 + srow) * K + swz;
  const short* Wsrc = W + (size_t)(n0 + srow) * K + swz;
  size_t l64K = (size_t)64 * K;

#define STAGE_(buf, k0)                                      \
  do {                                                       \
    gload_lds16(Asrc + (k0),        &As[buf][tid * 8]);      \
    gload_lds16(Asrc + l64K + (k0), &As[buf][4096 + tid * 8]); \
    gload_lds16(Wsrc + (k0),        &Ws[buf][tid * 8]);      \
    gload_lds16(Wsrc + l64K + (k0), &Ws[buf][4096 + tid * 8]); \
  } while (0)

#define COMPUTE_(bb)                                                          \
  do {                                                                        \
    bf16x8 af[4][2], bfr[2][2];                                               \
    _Pragma("unroll")                                                         \
    for (int mi = 0; mi < 4; ++mi)                                            \
      _Pragma("unroll")                                                       \
      for (int kk = 0; kk < 2; ++kk)                                          \
        af[mi][kk] = *(const bf16x8*)(&As[bb][(wm * 64 + mi * 16 + fr) * 64 + \
                                              (((kk << 2) + fq) ^ fp) * 8]);  \
    _Pragma("unroll")                                                         \
    for (int ni = 0; ni < 2; ++ni)                                            \
      _Pragma("unroll")                                                       \
      for (int kk = 0; kk < 2; ++kk)                                          \
        bfr[ni][kk] = *(const bf16x8*)(&Ws[bb][(wn * 32 + ni * 16 + fr) * 64 + \
                                               (((kk << 2) + fq) ^ fp) * 8]); \
    __builtin_amdgcn_s_setprio(1);                                            \
    _Pragma("unroll")                                                         \
    for (int mi = 0; mi < 4; ++mi)                                            \
      _Pragma("unroll")                                                       \
      for (int ni = 0; ni < 2; ++ni)                                          \
        _Pragma("unroll")                                                     \
        for (int kk = 0; kk < 2; ++kk)                                        \
          acc[mi][ni] = __builtin_amdgcn_mfma_f32_16x16x32_bf16(              \
              af[mi][kk], bfr[ni][kk], acc[mi][ni], 0, 0, 0);                 \
    __builtin_amdgcn_s_setprio(0);                                            \
  } while (0)

  int nt = K >> 6;
  STAGE_(0, 0);
  STAGE_(1, 64);
  int cur = 0;
  for (int t = 0; t < nt - 1; ++t) {
    asm volatile("s_waitcnt vmcnt(4)" ::: "memory");  // tile t landed; t+1 in flight
    __builtin_amdgcn_s_barrier();
    COMPUTE_(cur);
    asm volatile("s_waitcnt lgkmcnt(0)" ::: "memory"); // reads of cur done
    __builtin_amdgcn_s_barrier();
    if (t < nt - 2) STAGE_(cur, (size_t)(t + 2) * 64);
    cur ^= 1;
  }
  asm volatile("s_waitcnt vmcnt(0)" ::: "memory");
  __builtin_amdgcn_s_barrier();
  COMPUTE_(cur);

#undef STAGE_
#undef COMPUTE_

  #pragma unroll
  for (int mi = 0; mi < 4; ++mi) {
    #pragma unroll
    for (int ni = 0; ni < 2; ++ni) {
      int gm0 = m0 + wm * 64 + mi * 16 + fq * 4;
      int gn  = n0 + wn * 32 + ni * 16 + fr;
      float bv = bias[gn];
      #pragma unroll
      for (int j = 0; j < 4; ++j) {
        size_t idx = (size_t)(gm0 + j) * N + gn;
        float v = acc[mi][ni][j] + bv;
        if (EPI == 0)      ((short*)outv)[idx] = f2bf(v);
        else if (EPI == 1) ((float*)outv)[idx] = v + res[idx];
        else               ((short*)outv)[idx] = f2bf(gelu_f(v));
      }
    }
  }
}

// ---------------- causal flash attention (swapped-operand) ----------------
// QBLK=128 (4 waves x 32 q-rows as 2 fragment-groups), KVBLK=64.
// Counted-vmcnt pipeline (T4): per iter {V_WRITE(cur); issue V_LOAD/K_STAGE
// for t+1; s_waitcnt vmcnt(4); lgkmcnt(0)+s_barrier; compute; s_barrier}.
// No vmcnt(0) drain in the loop -> K/V fetch latency hides under compute.
__global__ __launch_bounds__(256, 3) void k_attn(const short* __restrict__ qkv,
                                                 short* __restrict__ out) {
  __shared__ short Kt[2][64 * 64];   // [key][d] swizzled via global src
  __shared__ short Vt[2][64 * 64];   // V^T [d][key] swizzled
  __shared__ short Pl[4][2048];      // per-wave P (2 q-groups), reused for O
  int tid  = threadIdx.x;
  int lane = tid & 63, w = tid >> 6;
  int qb   = (int)gridDim.x - 1 - (int)blockIdx.x;   // heavy blocks first
  int q0   = qb * 128;
  int bh   = blockIdx.y;
  int b    = bh >> 4, h = bh & 15;
  int fr   = lane & 15, fq = lane >> 4, fk = fq * 8;
  const float sc = 0.18033688011112042f;   // 0.125 * log2(e) (exp2 domain)

  // Q fragments: group g2 covers q-rows q0+w*32+g2*16+fr
  bf16x8 qa[2][2];
  #pragma unroll
  for (int g2 = 0; g2 < 2; ++g2) {
    const short* qp = qkv + (size_t)(b * S_ + q0 + w * 32 + g2 * 16 + fr) * TE_ + h * 64;
    qa[g2][0] = *(const bf16x8*)(qp + fk);
    qa[g2][1] = *(const bf16x8*)(qp + 32 + fk);
  }

  float m_r[2] = {-__builtin_inff(), -__builtin_inff()};
  float l_r[2] = {0.f, 0.f};
  f32x4 o[2][4];
  #pragma unroll
  for (int g2 = 0; g2 < 2; ++g2)
    #pragma unroll
    for (int c = 0; c < 4; ++c) o[g2][c] = (f32x4){0.f, 0.f, 0.f, 0.f};

  int srow = tid >> 3;      // staging row 0..31 (+32 on round 1)
  int schunk = tid & 7;     // 16B chunk within 128B row
  short* Pw = &Pl[w][0];
  bf16x8 vv[2];

#define V_LOAD_(kvv)                                                          \
  do {                                                                        \
    _Pragma("unroll")                                                         \
    for (int r = 0; r < 2; ++r) {                                             \
      size_t grow = (size_t)(b * S_ + (kvv) + srow + 32 * r) * TE_ + h * 64;  \
      vv[r] = *(const bf16x8*)(qkv + grow + 2 * E_ + (schunk << 3));          \
    }                                                                         \
  } while (0)

#define K_STAGE_(buf, kvv)                                                    \
  do {                                                                        \
    _Pragma("unroll")                                                         \
    for (int r = 0; r < 2; ++r) {                                             \
      size_t grow = (size_t)(b * S_ + (kvv) + srow + 32 * r) * TE_ + h * 64;  \
      gload_lds16(qkv + grow + E_ + ((schunk ^ (srow & 7)) << 3),             \
                  &Kt[buf][r * 2048 + tid * 8]);                              \
    }                                                                         \
  } while (0)

#define V_WRITE_(buf)                                                         \
  do {                                                                        \
    _Pragma("unroll")                                                         \
    for (int r = 0; r < 2; ++r) {                                             \
      int row = srow + 32 * r;                                                \
      int kc = row >> 3, kwi = row & 7;                                       \
      _Pragma("unroll")                                                       \
      for (int j = 0; j < 8; ++j) {                                           \
        int d = (schunk << 3) + j;                                            \
        int csw = kc ^ (d & 7) ^ ((d >> 3) & 7);                              \
        Vt[buf][d * 64 + csw * 8 + kwi] = vv[r][j];                           \
      }                                                                       \
    }                                                                         \
  } while (0)

  // prologue: V(0)->regs, K(0)->LDS buf0 (in flight)
  V_LOAD_(0);
  K_STAGE_(0, 0);
  int cur = 0;
  int nt = 2 * qb + 2;

  for (int t = 0; t < nt; ++t) {
    int kv = t * 64;
    V_WRITE_(cur);                 // implicit vmcnt waits only the V(t) regs
    if (t + 1 < nt) {              // prefetch t+1: stays in flight over compute
      V_LOAD_((t + 1) * 64);
      K_STAGE_(cur ^ 1, (t + 1) * 64);
      asm volatile("s_waitcnt vmcnt(4)" ::: "memory");  // K(t) landed in LDS
    } else {
      asm volatile("s_waitcnt vmcnt(0)" ::: "memory");
    }
    asm volatile("s_waitcnt lgkmcnt(0)" ::: "memory");   // V_WRITE visible
    __builtin_amdgcn_s_barrier();
    asm volatile("" ::: "memory");

    // ---- K A-frags (shared by both q-groups) ----
    int sw = fr & 7;
    bf16x8 ka[4][2];
    #pragma unroll
    for (int g = 0; g < 4; ++g) {
      const short* kb = &Kt[cur][((g << 4) + fr) * 64];
      ka[g][0] = *(const bf16x8*)(kb + ((fq ^ sw) << 3));
      ka[g][1] = *(const bf16x8*)(kb + (((4 + fq) ^ sw) << 3));
    }
    // ---- S^T = K @ Q^T : lane owns q=fr (per group), keys 16g+4fq+jj ----
    f32x4 s[2][4];
    #pragma unroll
    for (int g2 = 0; g2 < 2; ++g2)
      #pragma unroll
      for (int g = 0; g < 4; ++g) {
        f32x4 t0 = (f32x4){0.f, 0.f, 0.f, 0.f};
        t0 = __builtin_amdgcn_mfma_f32_16x16x32_bf16(ka[g][0], qa[g2][0], t0, 0, 0, 0);
        t0 = __builtin_amdgcn_mfma_f32_16x16x32_bf16(ka[g][1], qa[g2][1], t0, 0, 0, 0);
        s[g2][g] = t0;
      }
    #pragma unroll
    for (int g2 = 0; g2 < 2; ++g2)
      #pragma unroll
      for (int g = 0; g < 4; ++g)
        #pragma unroll
        for (int jj = 0; jj < 4; ++jj) s[g2][g][jj] *= sc;

    if (kv + 64 > q0) {            // diagonal region (block-uniform test)
      #pragma unroll
      for (int g2 = 0; g2 < 2; ++g2) {
        int qr = (q0 - kv) + 32 * w + 16 * g2 + fr;
        #pragma unroll
        for (int g = 0; g < 4; ++g)
          #pragma unroll
          for (int jj = 0; jj < 4; ++jj)
            if (16 * g + 4 * fq + jj > qr) s[g2][g][jj] = -__builtin_inff();
      }
    }

    // ---- online softmax per q-group: in-lane tree + 2 shfl ----
    #pragma unroll
    for (int g2 = 0; g2 < 2; ++g2) {
      float mg0 = fmaxf(fmaxf(s[g2][0][0], s[g2][0][1]), fmaxf(s[g2][0][2], s[g2][0][3]));
      float mg1 = fmaxf(fmaxf(s[g2][1][0], s[g2][1][1]), fmaxf(s[g2][1][2], s[g2][1][3]));
      float mg2 = fmaxf(fmaxf(s[g2][2][0], s[g2][2][1]), fmaxf(s[g2][2][2], s[g2][2][3]));
      float mg3 = fmaxf(fmaxf(s[g2][3][0], s[g2][3][1]), fmaxf(s[g2][3][2], s[g2][3][3]));
      float mt = fmaxf(fmaxf(mg0, mg1), fmaxf(mg2, mg3));
      mt = fmaxf(mt, __shfl_xor(mt, 16));
      mt = fmaxf(mt, __shfl_xor(mt, 32));
      float mn = fmaxf(m_r[g2], mt);
      float al = exp2_fast(m_r[g2] - mn);
      m_r[g2] = mn;
      #pragma unroll
      for (int g = 0; g < 4; ++g)
        #pragma unroll
        for (int jj = 0; jj < 4; ++jj) s[g2][g][jj] = exp2_fast(s[g2][g][jj] - mn);
      f32x4 s4 = s[g2][0] + s[g2][1] + s[g2][2] + s[g2][3];
      float ps = (s4[0] + s4[1]) + (s4[2] + s4[3]);
      ps += __shfl_xor(ps, 16);
      ps += __shfl_xor(ps, 32);
      l_r[g2] = l_r[g2] * al + ps;

      // P -> per-wave LDS (bf16, swizzled b64 stores)
      #pragma unroll
      for (int g = 0; g < 4; ++g) {
        short4v pk = { f2bf(s[g2][g][0]), f2bf(s[g2][g][1]),
                       f2bf(s[g2][g][2]), f2bf(s[g2][g][3]) };
        int pc = (2 * g + (fq >> 1)) ^ (fr & 7);
        *(short4v*)(Pw + g2 * 1024 + fr * 64 + pc * 8 + ((fq & 1) << 2)) = pk;
      }
      // rescale O (lane-local)
      #pragma unroll
      for (int c = 0; c < 4; ++c)
        #pragma unroll
        for (int jj = 0; jj < 4; ++jj) o[g2][c][jj] *= al;
    }

    // ---- O^T += V^T @ P^T : C[d][q]; V A-frags shared across groups ----
    bf16x8 pb[2][2];
    #pragma unroll
    for (int g2 = 0; g2 < 2; ++g2) {
      pb[g2][0] = *(const bf16x8*)(Pw + g2 * 1024 + fr * 64 + ((fq ^ (fr & 7)) << 3));
      pb[g2][1] = *(const bf16x8*)(Pw + g2 * 1024 + fr * 64 + (((4 + fq) ^ (fr & 7)) << 3));
    }
    #pragma unroll
    for (int c = 0; c < 4; ++c) {
      int d = 16 * c + fr;
      int sbase = (d & 7) ^ ((d >> 3) & 7);
      const short* vb = &Vt[cur][d * 64];
      bf16x8 va0 = *(const bf16x8*)(vb + ((fq ^ sbase) << 3));
      bf16x8 va1 = *(const bf16x8*)(vb + (((4 + fq) ^ sbase) << 3));
      #pragma unroll
      for (int g2 = 0; g2 < 2; ++g2) {
        o[g2][c] = __builtin_amdgcn_mfma_f32_16x16x32_bf16(va0, pb[g2][0], o[g2][c], 0, 0, 0);
        o[g2][c] = __builtin_amdgcn_mfma_f32_16x16x32_bf16(va1, pb[g2][1], o[g2][c], 0, 0, 0);
      }
    }

    __builtin_amdgcn_s_barrier();   // all waves done reading buf cur
    asm volatile("" ::: "memory");
    cur ^= 1;
  }

#undef V_LOAD_
#undef K_STAGE_
#undef V_WRITE_

  // ---- epilogue: O^T -> LDS (per-wave, swizzled) -> coalesced global ----
  int ql = lane >> 2, dc = lane & 3;
  int swz = ql & 7;
  #pragma unroll
  for (int g2 = 0; g2 < 2; ++g2) {
    float inv_l = 1.0f / l_r[g2];
    #pragma unroll
    for (int c = 0; c < 4; ++c) {
      short4v okk = { f2bf(o[g2][c][0] * inv_l), f2bf(o[g2][c][1] * inv_l),
                      f2bf(o[g2][c][2] * inv_l), f2bf(o[g2][c][3] * inv_l) };
      int pc = (2 * c + (fq >> 1)) ^ (fr & 7);
      *(short4v*)(Pw + g2 * 1024 + fr * 64 + pc * 8 + ((fq & 1) << 2)) = okk;
    }
    const short* ob = Pw + g2 * 1024 + ql * 64;
    bf16x8 r0 = *(const bf16x8*)(ob + (((2 * dc) ^ swz) << 3));
    bf16x8 r1 = *(const bf16x8*)(ob + (((2 * dc + 1) ^ swz) << 3));
    short* op = out + (size_t)(b * S_ + q0 + 32 * w + 16 * g2 + ql) * E_ + h * 64 + dc * 16;
    *(bf16x8*)op = r0;
    *(bf16x8*)(op + 8) = r1;
  }
}

// ---------------- launch ----------------
extern "C" void kernel_launch(void* const* d_in, const int* in_sizes, int n_in,
                              void* d_out, int out_size, void* d_ws, size_t ws_size,
                              hipStream_t stream) {
  const float* x      = (const float*)d_in[0];
  const float* ln1_w  = (const float*)d_in[1];
  const float* ln1_b  = (const float*)d_in[2];
  const float* qkv_w  = (const float*)d_in[3];
  const float* qkv_b  = (const float*)d_in[4];
  const float* proj_w = (const float*)d_in[5];
  const float* proj_b = (const float*)d_in[6];
  const float* ln2_w  = (const float*)d_in[7];
  const float* ln2_b  = (const float*)d_in[8];
  const float* fc1_w  = (const float*)d_in[9];
  const float* fc1_b  = (const float*)d_in[10];
  const float* fc2_w  = (const float*)d_in[11];
  const float* fc2_b  = (const float*)d_in[12];
  float* out = (float*)d_out;

  char* ws = (char*)d_ws;
  // Timeline-overlapped layout (80 MB total):
  short* xn1    = (short*)(ws + 0);              // 8 MB  (dead after qkv gemm)
  short* qkvb   = (short*)(ws + (8u  << 20));    // 24 MB (dead after attn)
  short* gelu_o = (short*)(ws + 0);              // 32 MB (reuses xn1+qkvb)
  short* attn_o = (short*)(ws + (32u << 20));    // 8 MB  (dead after proj gemm)
  short* h_ln2  = (short*)(ws + (32u << 20));    // 8 MB  (reuses attn_o)
  float* x_res  = (float*)(ws + (40u << 20));    // 16 MB fp32
  short* w_qkv  = (short*)(ws + (56u << 20));    // 6 MB
  short* w_proj = (short*)(ws + (62u << 20));    // 2 MB
  short* w_fc1  = (short*)(ws + (64u << 20));    // 8 MB
  short* w_fc2  = (short*)(ws + (72u << 20));    // 8 MB

  k_cvt4<<<dim3(4096, 4), 256, 0, stream>>>(qkv_w, w_qkv, 786432,
                                            proj_w, w_proj, 262144,
                                            fc1_w, w_fc1, 1048576,
                                            fc2_w, w_fc2, 1048576);

  k_ln<<<MROWS, 256, 0, stream>>>(x, ln1_w, ln1_b, xn1);
  k_gemm<0><<<dim3(24, 32), 512, 0, stream>>>(xn1, w_qkv, qkv_b, nullptr, qkvb,
                                              MROWS, TE_, E_);
  k_attn<<<dim3(S_ / 128, B_ * H_), 256, 0, stream>>>(qkvb, attn_o);
  k_gemm<1><<<dim3(8, 32), 512, 0, stream>>>(attn_o, w_proj, proj_b, x, x_res,
                                             MROWS, E_, E_);
  k_ln<<<MROWS, 256, 0, stream>>>(x_res, ln2_w, ln2_b, h_ln2);
  k_gemm<2><<<dim3(32, 32), 512, 0, stream>>>(h_ln2, w_fc1, fc1_b, nullptr, gelu_o,
                                              MROWS, 4096, E_);
  k_gemm<1><<<dim3(8, 32), 512, 0, stream>>>(gelu_o, w_fc2, fc2_b, x_res, out,
                                             MROWS, E_, 4096);
}